// Round 3
// baseline (122.421 us; speedup 1.0000x reference)
//
#include <hip/hip_runtime.h>

#define B 16
#define P 32768
#define NG 128
#define KTOP 4
#define TILE 256
#define NT (P / TILE)            // 128 tiles per batch
#define SAMP 2048                // threshold sample size

typedef unsigned long long u64;
typedef unsigned int u32;

__device__ __forceinline__ void ceu(u64 &x, u64 &y) {
    u64 a = x, b = y; bool gt = a > b;
    x = gt ? a : b;  y = gt ? b : a;
}
__device__ __forceinline__ void cef(float &x, float &y) {
    float h = fmaxf(x, y), l = fminf(x, y); x = h; y = l;
}

// branchless stable sorted-desc top-4 insert of key x
#define INS4(x, a0, a1, a2, a3)                                   \
    {                                                             \
        bool g0 = (x) > a0, g1 = (x) > a1, g2 = (x) > a2, g3 = (x) > a3; \
        u64 n3 = g2 ? a2 : (g3 ? (x) : a3);                       \
        u64 n2 = g1 ? a1 : (g2 ? (x) : a2);                       \
        u64 n1 = g0 ? a0 : (g1 ? (x) : a1);                       \
        u64 n0 = g0 ? (x) : a0;                                   \
        a0 = n0; a1 = n1; a2 = n2; a3 = n3;                       \
    }

// ---------- kernel 1: per-(b,g) threshold tau = 4th-best IoU over priors [0,SAMP) ----------
// Sample 4th-best <= full 4th-best, so {iou >= tau} is a superset of the true top-4.
__global__ __launch_bounds__(256)
void k_tau(const float* __restrict__ rois, const float* __restrict__ targets,
           float* __restrict__ tau)
{
    #pragma clang fp contract(off)
    const int blk = blockIdx.x;                 // B*NG = 2048
    const int b = blk >> 7, g = blk & (NG - 1);
    const int tid = threadIdx.x, lane = tid & 63, wv = tid >> 6;

    const float4 t = *(const float4*)(targets + ((size_t)(b * NG + g)) * 4);
    const float areaT = (t.z - t.x) * (t.w - t.y);
    const float4* __restrict__ pv = (const float4*)(rois + ((size_t)(2 * b + 1)) * P * 4);

    __shared__ float sf[4][4];
    float w0 = -1.f, w1 = -1.f, w2 = -1.f, w3 = -1.f;
    #pragma unroll
    for (int it = 0; it < SAMP / 256; ++it) {
        float4 q = pv[it * 256 + tid];
        float ap = (q.z - q.x) * (q.w - q.y);
        float ltx = fmaxf(t.x, q.x), lty = fmaxf(t.y, q.y);
        float rbx = fminf(t.z, q.z), rby = fminf(t.w, q.w);
        float wx = fmaxf(rbx - ltx, 0.0f);
        float wy = fmaxf(rby - lty, 0.0f);
        float inter = wx * wy;
        float iou = inter / ((areaT + ap) - inter);
        float x = iou, hh;
        hh = fmaxf(w0, x); x = fminf(w0, x); w0 = hh;
        hh = fmaxf(w1, x); x = fminf(w1, x); w1 = hh;
        hh = fmaxf(w2, x); x = fminf(w2, x); w2 = hh;
        w3 = fmaxf(w3, x);
    }
    #pragma unroll
    for (int d = 32; d >= 1; d >>= 1) {
        float n0 = __shfl_down(w0, d, 64);
        float n1 = __shfl_down(w1, d, 64);
        float n2 = __shfl_down(w2, d, 64);
        float n3 = __shfl_down(w3, d, 64);
        cef(w0, n3); cef(w1, n2); cef(w2, n1); cef(w3, n0);
        cef(w0, w2); cef(w1, w3); cef(w0, w1); cef(w2, w3);
    }
    if (lane == 0) { sf[wv][0] = w0; sf[wv][1] = w1; sf[wv][2] = w2; sf[wv][3] = w3; }
    __syncthreads();
    if (tid == 0) {
        float m0 = -1.f, m1 = -1.f, m2 = -1.f, m3 = -1.f;
        #pragma unroll
        for (int j = 0; j < 16; ++j) {
            float x = sf[j >> 2][j & 3], hh;
            hh = fmaxf(m0, x); x = fminf(m0, x); m0 = hh;
            hh = fmaxf(m1, x); x = fminf(m1, x); m1 = hh;
            hh = fmaxf(m2, x); x = fminf(m2, x); m2 = hh;
            m3 = fmaxf(m3, x);
        }
        tau[blk] = m3;
    }
}

// ---------- kernel 2: dense filtered scan, TWO-PHASE ----------
// Phase 1: pure division-free filter (iou>=tau <=> inter >= slope*(areaT+areaP),
// slope conservatively shrunk 2e-4 >> ~5e-7 fp error) -> per-lane survivor BITMASK.
// No divide, no u64 insert in this loop, so there is nothing for the compiler to
// if-convert (R1/R2 lesson: predicated slow path executed every iter, 3x cost).
// Phase 2: divergent while(mask) loop (loops cannot be if-converted): pop bit,
// re-read prior from LDS, exact IEEE IoU (bit-identical to reference), INS4.
// Expected survivors ~0.25/lane/tile -> phase 2 is ~2-3 wave-trips.
__global__ __launch_bounds__(256, 8)
void k_scan(const float* __restrict__ rois, const float* __restrict__ targets,
            const float* __restrict__ tau, u64* __restrict__ part)
{
    #pragma clang fp contract(off)
    const int blk = blockIdx.x;                 // B*NT = 2048
    const int b = blk / NT, tile = blk & (NT - 1);
    const int tid = threadIdx.x;
    const int g = tid & (NG - 1), hf = tid >> 7;

    __shared__ float4 sQ[TILE];                 // 4 KB
    __shared__ float  sA[TILE];                 // 1 KB
    __shared__ u64    sm[NG][4];                // 4 KB

    const float4* __restrict__ pv =
        (const float4*)(rois + ((size_t)(2 * b + 1)) * P * 4) + (size_t)tile * TILE;
    {
        float4 q = pv[tid];
        sQ[tid] = q;
        sA[tid] = (q.z - q.x) * (q.w - q.y);    // same expr as reference area_p
    }

    const float4 t = *(const float4*)(targets + ((size_t)(b * NG + g)) * 4);
    const float areaT = (t.z - t.x) * (t.w - t.y);
    const float tv    = tau[b * NG + g];
    const float slope = (tv / (1.0f + tv)) * (1.0f - 2e-4f);
    const float cA    = slope * areaT;
    __syncthreads();

    const int base = hf * (TILE / 2);

    // ---- phase 1: build survivor bitmasks (lean loop, VALU floor) ----
    u64 msk0 = 0, msk1 = 0;
    #pragma unroll
    for (int j = 0; j < 64; ++j) {
        const float4 q = sQ[base + j];
        const float ap = sA[base + j];
        float ltx = fmaxf(t.x, q.x), lty = fmaxf(t.y, q.y);
        float rbx = fminf(t.z, q.z), rby = fminf(t.w, q.w);
        float wx = fmaxf(rbx - ltx, 0.0f);
        float wy = fmaxf(rby - lty, 0.0f);
        float inter = wx * wy;
        bool pass = inter >= __builtin_fmaf(slope, ap, cA);
        msk0 |= ((u64)pass) << j;
    }
    #pragma unroll
    for (int j = 0; j < 64; ++j) {
        const float4 q = sQ[base + 64 + j];
        const float ap = sA[base + 64 + j];
        float ltx = fmaxf(t.x, q.x), lty = fmaxf(t.y, q.y);
        float rbx = fminf(t.z, q.z), rby = fminf(t.w, q.w);
        float wx = fmaxf(rbx - ltx, 0.0f);
        float wy = fmaxf(rby - lty, 0.0f);
        float inter = wx * wy;
        bool pass = inter >= __builtin_fmaf(slope, ap, cA);
        msk1 |= ((u64)pass) << j;
    }

    // ---- phase 2: rare exact path over survivor bits ----
    u64 a0 = 0, a1 = 0, a2 = 0, a3 = 0;         // key 0 = strict minimum
    const u32 gbase = (u32)(tile * TILE + base);
    #pragma clang loop unroll(disable)
    for (int c = 0; c < 2; ++c) {
        u64 m = c ? msk1 : msk0;
        const int coff = c << 6;
        while (m) {                              // divergent loop: real branches
            int j = __builtin_ctzll(m);
            m &= m - 1;
            const int idx = base + coff + j;
            const float4 q = sQ[idx];
            const float ap = sA[idx];
            float ltx = fmaxf(t.x, q.x), lty = fmaxf(t.y, q.y);
            float rbx = fminf(t.z, q.z), rby = fminf(t.w, q.w);
            float wx = fmaxf(rbx - ltx, 0.0f);
            float wy = fmaxf(rby - lty, 0.0f);
            float inter = wx * wy;
            float iou = inter / ((areaT + ap) - inter);   // bit-exact vs reference
            u64 x = ((u64)__float_as_uint(iou) << 32) | (u32)(~(gbase + (u32)(coff + j)));
            INS4(x, a0, a1, a2, a3);
        }
    }

    // merge the two halves of each truth, write per-(b,tile,g) sorted top-4
    if (hf == 1) { sm[g][0] = a0; sm[g][1] = a1; sm[g][2] = a2; sm[g][3] = a3; }
    __syncthreads();
    if (hf == 0) {
        u64 b0 = sm[g][0], b1 = sm[g][1], b2 = sm[g][2], b3 = sm[g][3];
        ceu(a0, b3); ceu(a1, b2); ceu(a2, b1); ceu(a3, b0);
        ceu(a0, a2); ceu(a1, a3); ceu(a0, a1); ceu(a2, a3);
        u64* dst = part + (((size_t)b * NT + tile) * NG + g) * KTOP;
        dst[0] = a0; dst[1] = a1; dst[2] = a2; dst[3] = a3;
    }
}

// ---------- kernel 3: merge 128 tile-partials per (b,g), encode, write ----------
__global__ __launch_bounds__(64)
void k_top(const float* __restrict__ rois, const float* __restrict__ targets,
           const u64* __restrict__ part, float* __restrict__ out)
{
    #pragma clang fp contract(off)
    const int blk = blockIdx.x;                 // B*NG = 2048
    const int b = blk >> 7, g = blk & (NG - 1);
    const int lane = threadIdx.x;               // lane = tile index (x2)

    const u64* __restrict__ s0 = part + (((size_t)b * NT + lane) * NG + g) * KTOP;
    const u64* __restrict__ s1 = part + (((size_t)b * NT + lane + 64) * NG + g) * KTOP;
    u64 a0 = s0[0], a1 = s0[1], a2 = s0[2], a3 = s0[3];
    u64 b0 = s1[0], b1 = s1[1], b2 = s1[2], b3 = s1[3];
    ceu(a0, b3); ceu(a1, b2); ceu(a2, b1); ceu(a3, b0);
    ceu(a0, a2); ceu(a1, a3); ceu(a0, a1); ceu(a2, a3);
    #pragma unroll
    for (int d = 32; d >= 1; d >>= 1) {
        u64 n0 = __shfl_down(a0, d, 64);
        u64 n1 = __shfl_down(a1, d, 64);
        u64 n2 = __shfl_down(a2, d, 64);
        u64 n3 = __shfl_down(a3, d, 64);
        ceu(a0, n3); ceu(a1, n2); ceu(a2, n1); ceu(a3, n0);
        ceu(a0, a2); ceu(a1, a3); ceu(a0, a1); ceu(a2, a3);
    }
    if (lane == 0) {
        const float4 t = *(const float4*)(targets + ((size_t)(b * NG + g)) * 4);
        const float t0 = t.x, t1 = t.y, t2 = t.z, t3 = t.w;
        const float gw = t2 - t0, gh = t3 - t1;
        const float gcx = (t0 + t2) * 0.5f;
        const float gcy = (t1 + t3) * 0.5f;
        const float4* __restrict__ pv =
            (const float4*)(rois + ((size_t)(2 * b + 1)) * P * 4);
        float4* __restrict__ o4 = (float4*)out;

        u64 ks[KTOP] = {a0, a1, a2, a3};
        #pragma unroll
        for (int k = 0; k < KTOP; ++k) {
            int idx = (int)(~(u32)ks[k]) & (P - 1);
            float4 q = pv[idx];
            float pcx = (q.x + q.z) * 0.5f;
            float pcy = (q.y + q.w) * 0.5f;
            float pw  = q.z - q.x;
            float ph  = q.w - q.y;
            float4 r;
            r.x = (gcx - pcx) / (0.1f * pw);
            r.y = (gcy - pcy) / (0.1f * ph);
            r.z = logf(gw / pw) / 0.2f;
            r.w = logf(gh / ph) / 0.2f;
            o4[((size_t)(b * NG + g)) * KTOP + k] = r;
        }
    }
}

extern "C" void kernel_launch(void* const* d_in, const int* in_sizes, int n_in,
                              void* d_out, int out_size, void* d_ws, size_t ws_size,
                              hipStream_t stream) {
    const float* rois    = (const float*)d_in[0];
    const float* targets = (const float*)d_in[1];
    float* out = (float*)d_out;

    float* tau  = (float*)d_ws;                       // 8 KB
    u64*   part = (u64*)((char*)d_ws + 8192);         // 16*128*128*4*8 = 8 MB

    k_tau <<<dim3(B * NG), dim3(256), 0, stream>>>(rois, targets, tau);
    k_scan<<<dim3(B * NT), dim3(256), 0, stream>>>(rois, targets, tau, part);
    k_top <<<dim3(B * NG), dim3(64),  0, stream>>>(rois, targets, part, out);
}

// Round 4
// 115.502 us; speedup vs baseline: 1.0599x; 1.0599x over previous
//
#include <hip/hip_runtime.h>

#define B 16
#define P 32768
#define NG 128
#define KTOP 4
#define TILE 256
#define NT (P / TILE)            // 128 tiles per batch
#define SAMP 2048                // threshold sample size

typedef unsigned long long u64;
typedef unsigned int u32;

__device__ __forceinline__ void ceu(u64 &x, u64 &y) {
    u64 a = x, b = y; bool gt = a > b;
    x = gt ? a : b;  y = gt ? b : a;
}
__device__ __forceinline__ void cef(float &x, float &y) {
    float h = fmaxf(x, y), l = fminf(x, y); x = h; y = l;
}

// branchless stable sorted-desc top-4 insert of key x
#define INS4(x, a0, a1, a2, a3)                                   \
    {                                                             \
        bool g0 = (x) > a0, g1 = (x) > a1, g2 = (x) > a2, g3 = (x) > a3; \
        u64 n3 = g2 ? a2 : (g3 ? (x) : a3);                       \
        u64 n2 = g1 ? a1 : (g2 ? (x) : a2);                       \
        u64 n1 = g0 ? a0 : (g1 ? (x) : a1);                       \
        u64 n0 = g0 ? (x) : a0;                                   \
        a0 = n0; a1 = n1; a2 = n2; a3 = n3;                       \
    }

// ---------- kernel 1: per-(b,g) threshold tau = 4th-best IoU over priors [0,SAMP) ----------
// Sample 4th-best <= full 4th-best, so {iou >= tau} is a superset of the true top-4.
__global__ __launch_bounds__(256)
void k_tau(const float* __restrict__ rois, const float* __restrict__ targets,
           float* __restrict__ tau)
{
    #pragma clang fp contract(off)
    const int blk = blockIdx.x;                 // B*NG = 2048
    const int b = blk >> 7, g = blk & (NG - 1);
    const int tid = threadIdx.x, lane = tid & 63, wv = tid >> 6;

    const float4 t = *(const float4*)(targets + ((size_t)(b * NG + g)) * 4);
    const float areaT = (t.z - t.x) * (t.w - t.y);
    const float4* __restrict__ pv = (const float4*)(rois + ((size_t)(2 * b + 1)) * P * 4);

    __shared__ float sf[4][4];
    float w0 = -1.f, w1 = -1.f, w2 = -1.f, w3 = -1.f;
    #pragma unroll
    for (int it = 0; it < SAMP / 256; ++it) {
        float4 q = pv[it * 256 + tid];
        float ap = (q.z - q.x) * (q.w - q.y);
        float ltx = fmaxf(t.x, q.x), lty = fmaxf(t.y, q.y);
        float rbx = fminf(t.z, q.z), rby = fminf(t.w, q.w);
        float wx = fmaxf(rbx - ltx, 0.0f);
        float wy = fmaxf(rby - lty, 0.0f);
        float inter = wx * wy;
        float iou = inter / ((areaT + ap) - inter);
        float x = iou, hh;
        hh = fmaxf(w0, x); x = fminf(w0, x); w0 = hh;
        hh = fmaxf(w1, x); x = fminf(w1, x); w1 = hh;
        hh = fmaxf(w2, x); x = fminf(w2, x); w2 = hh;
        w3 = fmaxf(w3, x);
    }
    #pragma unroll
    for (int d = 32; d >= 1; d >>= 1) {
        float n0 = __shfl_down(w0, d, 64);
        float n1 = __shfl_down(w1, d, 64);
        float n2 = __shfl_down(w2, d, 64);
        float n3 = __shfl_down(w3, d, 64);
        cef(w0, n3); cef(w1, n2); cef(w2, n1); cef(w3, n0);
        cef(w0, w2); cef(w1, w3); cef(w0, w1); cef(w2, w3);
    }
    if (lane == 0) { sf[wv][0] = w0; sf[wv][1] = w1; sf[wv][2] = w2; sf[wv][3] = w3; }
    __syncthreads();
    if (tid == 0) {
        float m0 = -1.f, m1 = -1.f, m2 = -1.f, m3 = -1.f;
        #pragma unroll
        for (int j = 0; j < 16; ++j) {
            float x = sf[j >> 2][j & 3], hh;
            hh = fmaxf(m0, x); x = fminf(m0, x); m0 = hh;
            hh = fmaxf(m1, x); x = fminf(m1, x); m1 = hh;
            hh = fmaxf(m2, x); x = fminf(m2, x); m2 = hh;
            m3 = fmaxf(m3, x);
        }
        tau[blk] = m3;
    }
}

// ---------- kernel 2: dense filtered scan, TWO-PHASE ----------
// Phase 1: pure division-free filter -> per-lane survivor BITMASK (constant shifts
// via full unroll). Phase 2: divergent while(mask) pop-bit loop with exact IEEE IoU.
// R3 lesson: __launch_bounds__(256,8) capped VGPRs at 64; the fully-unrolled
// phase-1 loops spilled to scratch (HBM) -> no speedup AND harness fills slowed
// ~10% (spill traffic). (256,4) gives a 128-VGPR budget: payload fits, no spill.
// Occupancy 4 blocks/CU was already proven sufficient to be VALU-bound (R1, 70%).
__global__ __launch_bounds__(256, 4)
void k_scan(const float* __restrict__ rois, const float* __restrict__ targets,
            const float* __restrict__ tau, u64* __restrict__ part)
{
    #pragma clang fp contract(off)
    const int blk = blockIdx.x;                 // B*NT = 2048
    const int b = blk / NT, tile = blk & (NT - 1);
    const int tid = threadIdx.x;
    const int g = tid & (NG - 1), hf = tid >> 7;

    __shared__ float4 sQ[TILE];                 // 4 KB
    __shared__ float  sA[TILE];                 // 1 KB
    __shared__ u64    sm[NG][4];                // 4 KB

    const float4* __restrict__ pv =
        (const float4*)(rois + ((size_t)(2 * b + 1)) * P * 4) + (size_t)tile * TILE;
    {
        float4 q = pv[tid];
        sQ[tid] = q;
        sA[tid] = (q.z - q.x) * (q.w - q.y);    // same expr as reference area_p
    }

    const float4 t = *(const float4*)(targets + ((size_t)(b * NG + g)) * 4);
    const float areaT = (t.z - t.x) * (t.w - t.y);
    const float tv    = tau[b * NG + g];
    const float slope = (tv / (1.0f + tv)) * (1.0f - 2e-4f);
    const float cA    = slope * areaT;
    __syncthreads();

    const int base = hf * (TILE / 2);

    // ---- phase 1: build survivor bitmasks (lean loop, VALU floor) ----
    u64 msk0 = 0, msk1 = 0;
    #pragma unroll
    for (int j = 0; j < 64; ++j) {
        const float4 q = sQ[base + j];
        const float ap = sA[base + j];
        float ltx = fmaxf(t.x, q.x), lty = fmaxf(t.y, q.y);
        float rbx = fminf(t.z, q.z), rby = fminf(t.w, q.w);
        float wx = fmaxf(rbx - ltx, 0.0f);
        float wy = fmaxf(rby - lty, 0.0f);
        float inter = wx * wy;
        bool pass = inter >= __builtin_fmaf(slope, ap, cA);
        msk0 |= ((u64)pass) << j;
    }
    #pragma unroll
    for (int j = 0; j < 64; ++j) {
        const float4 q = sQ[base + 64 + j];
        const float ap = sA[base + 64 + j];
        float ltx = fmaxf(t.x, q.x), lty = fmaxf(t.y, q.y);
        float rbx = fminf(t.z, q.z), rby = fminf(t.w, q.w);
        float wx = fmaxf(rbx - ltx, 0.0f);
        float wy = fmaxf(rby - lty, 0.0f);
        float inter = wx * wy;
        bool pass = inter >= __builtin_fmaf(slope, ap, cA);
        msk1 |= ((u64)pass) << j;
    }

    // ---- phase 2: rare exact path over survivor bits ----
    u64 a0 = 0, a1 = 0, a2 = 0, a3 = 0;         // key 0 = strict minimum
    const u32 gbase = (u32)(tile * TILE + base);
    #pragma clang loop unroll(disable)
    for (int c = 0; c < 2; ++c) {
        u64 m = c ? msk1 : msk0;
        const int coff = c << 6;
        while (m) {                              // divergent loop: real branches
            int j = __builtin_ctzll(m);
            m &= m - 1;
            const int idx = base + coff + j;
            const float4 q = sQ[idx];
            const float ap = sA[idx];
            float ltx = fmaxf(t.x, q.x), lty = fmaxf(t.y, q.y);
            float rbx = fminf(t.z, q.z), rby = fminf(t.w, q.w);
            float wx = fmaxf(rbx - ltx, 0.0f);
            float wy = fmaxf(rby - lty, 0.0f);
            float inter = wx * wy;
            float iou = inter / ((areaT + ap) - inter);   // bit-exact vs reference
            u64 x = ((u64)__float_as_uint(iou) << 32) | (u32)(~(gbase + (u32)(coff + j)));
            INS4(x, a0, a1, a2, a3);
        }
    }

    // merge the two halves of each truth, write per-(b,tile,g) sorted top-4
    if (hf == 1) { sm[g][0] = a0; sm[g][1] = a1; sm[g][2] = a2; sm[g][3] = a3; }
    __syncthreads();
    if (hf == 0) {
        u64 b0 = sm[g][0], b1 = sm[g][1], b2 = sm[g][2], b3 = sm[g][3];
        ceu(a0, b3); ceu(a1, b2); ceu(a2, b1); ceu(a3, b0);
        ceu(a0, a2); ceu(a1, a3); ceu(a0, a1); ceu(a2, a3);
        u64* dst = part + (((size_t)b * NT + tile) * NG + g) * KTOP;
        dst[0] = a0; dst[1] = a1; dst[2] = a2; dst[3] = a3;
    }
}

// ---------- kernel 3: merge 128 tile-partials per (b,g), encode, write ----------
__global__ __launch_bounds__(64)
void k_top(const float* __restrict__ rois, const float* __restrict__ targets,
           const u64* __restrict__ part, float* __restrict__ out)
{
    #pragma clang fp contract(off)
    const int blk = blockIdx.x;                 // B*NG = 2048
    const int b = blk >> 7, g = blk & (NG - 1);
    const int lane = threadIdx.x;               // lane = tile index (x2)

    const u64* __restrict__ s0 = part + (((size_t)b * NT + lane) * NG + g) * KTOP;
    const u64* __restrict__ s1 = part + (((size_t)b * NT + lane + 64) * NG + g) * KTOP;
    u64 a0 = s0[0], a1 = s0[1], a2 = s0[2], a3 = s0[3];
    u64 b0 = s1[0], b1 = s1[1], b2 = s1[2], b3 = s1[3];
    ceu(a0, b3); ceu(a1, b2); ceu(a2, b1); ceu(a3, b0);
    ceu(a0, a2); ceu(a1, a3); ceu(a0, a1); ceu(a2, a3);
    #pragma unroll
    for (int d = 32; d >= 1; d >>= 1) {
        u64 n0 = __shfl_down(a0, d, 64);
        u64 n1 = __shfl_down(a1, d, 64);
        u64 n2 = __shfl_down(a2, d, 64);
        u64 n3 = __shfl_down(a3, d, 64);
        ceu(a0, n3); ceu(a1, n2); ceu(a2, n1); ceu(a3, n0);
        ceu(a0, a2); ceu(a1, a3); ceu(a0, a1); ceu(a2, a3);
    }
    if (lane == 0) {
        const float4 t = *(const float4*)(targets + ((size_t)(b * NG + g)) * 4);
        const float t0 = t.x, t1 = t.y, t2 = t.z, t3 = t.w;
        const float gw = t2 - t0, gh = t3 - t1;
        const float gcx = (t0 + t2) * 0.5f;
        const float gcy = (t1 + t3) * 0.5f;
        const float4* __restrict__ pv =
            (const float4*)(rois + ((size_t)(2 * b + 1)) * P * 4);
        float4* __restrict__ o4 = (float4*)out;

        u64 ks[KTOP] = {a0, a1, a2, a3};
        #pragma unroll
        for (int k = 0; k < KTOP; ++k) {
            int idx = (int)(~(u32)ks[k]) & (P - 1);
            float4 q = pv[idx];
            float pcx = (q.x + q.z) * 0.5f;
            float pcy = (q.y + q.w) * 0.5f;
            float pw  = q.z - q.x;
            float ph  = q.w - q.y;
            float4 r;
            r.x = (gcx - pcx) / (0.1f * pw);
            r.y = (gcy - pcy) / (0.1f * ph);
            r.z = logf(gw / pw) / 0.2f;
            r.w = logf(gh / ph) / 0.2f;
            o4[((size_t)(b * NG + g)) * KTOP + k] = r;
        }
    }
}

extern "C" void kernel_launch(void* const* d_in, const int* in_sizes, int n_in,
                              void* d_out, int out_size, void* d_ws, size_t ws_size,
                              hipStream_t stream) {
    const float* rois    = (const float*)d_in[0];
    const float* targets = (const float*)d_in[1];
    float* out = (float*)d_out;

    float* tau  = (float*)d_ws;                       // 8 KB
    u64*   part = (u64*)((char*)d_ws + 8192);         // 16*128*128*4*8 = 8 MB

    k_tau <<<dim3(B * NG), dim3(256), 0, stream>>>(rois, targets, tau);
    k_scan<<<dim3(B * NT), dim3(256), 0, stream>>>(rois, targets, tau, part);
    k_top <<<dim3(B * NG), dim3(64),  0, stream>>>(rois, targets, part, out);
}